// Round 1
// baseline (88.871 us; speedup 1.0000x reference)
//
#include <hip/hip_runtime.h>

// Problem constants from the reference (B=4, N=1024, D=256).
#define N_DIM 1024
#define D_DIM 256

// One 64-lane wave per edge.
// Lane l loads float4 at element offset l*4 of both rows (row = 1KB, fully
// coalesced), computes 4 squared diffs, butterfly-reduces across 64 lanes,
// sqrt, and lanes 0..1 store the broadcast value as two float4 (out stride 8).
__global__ __launch_bounds__(256) void edge_dist_kernel(
    const float* __restrict__ x,
    const int* __restrict__ eb,
    const int* __restrict__ ei,
    const int* __restrict__ ej,
    float* __restrict__ out,
    int E)
{
    const int wave = (int)((blockIdx.x * (unsigned)blockDim.x + threadIdx.x) >> 6);
    if (wave >= E) return;  // wave-uniform exit (E tail)
    const int lane = (int)(threadIdx.x & 63u);

    const int b = eb[wave];
    const int i = ei[wave];
    const int j = ej[wave];

    const float4* rowi = reinterpret_cast<const float4*>(x + ((size_t)b * N_DIM + i) * D_DIM);
    const float4* rowj = reinterpret_cast<const float4*>(x + ((size_t)b * N_DIM + j) * D_DIM);

    const float4 a = rowi[lane];
    const float4 c = rowj[lane];
    const float dx = a.x - c.x;
    const float dy = a.y - c.y;
    const float dz = a.z - c.z;
    const float dw = a.w - c.w;
    float s = dx * dx + dy * dy + dz * dz + dw * dw;

    // 64-lane butterfly reduction
    #pragma unroll
    for (int off = 32; off >= 1; off >>= 1)
        s += __shfl_xor(s, off, 64);

    const float d = sqrtf(s);
    const float4 v = make_float4(d, d, d, d);
    if (lane < 2) {
        reinterpret_cast<float4*>(out + (size_t)wave * 8)[lane] = v;
    }
}

extern "C" void kernel_launch(void* const* d_in, const int* in_sizes, int n_in,
                              void* d_out, int out_size, void* d_ws, size_t ws_size,
                              hipStream_t stream) {
    const float* x  = (const float*)d_in[0];
    const int*   eb = (const int*)d_in[1];
    const int*   ei = (const int*)d_in[2];
    const int*   ej = (const int*)d_in[3];
    float* out = (float*)d_out;

    const int E = in_sizes[1];              // data-dependent edge count
    const int waves_per_block = 4;          // 256 threads = 4 waves
    const int blocks = (E + waves_per_block - 1) / waves_per_block;
    if (blocks > 0) {
        edge_dist_kernel<<<blocks, 256, 0, stream>>>(x, eb, ei, ej, out, E);
    }
}

// Round 2
// 30.399 us; speedup vs baseline: 2.9235x; 2.9235x over previous
//
#include <hip/hip_runtime.h>

// Problem constants from the reference (B=4, N=1024, D=256).
#define B_DIM 4
#define N_DIM 1024
#define D_DIM 256   // ej < 256 always (nonzero index over last dim of x)

// ---------------- Tile kernel: Z[b][i][j] = ||x[b,i]-x[b,j]||^2 ------------
// i in [0,1024), j in [0,256). Tiles: BM=64 (i), BN=32 (j), BK=16.
// Block = 256 threads; each thread computes 4(m) x 2(n) outputs.
// Grid = (256/BN=8, 1024/BM=16, B=4) = 512 blocks.
#define BM 64
#define BN 32
#define BK 16
#define PADA 4   // As row stride 68 floats (16B-aligned, ~2-way banks)
#define PADB 2   // Bs row stride 34 floats (8B-aligned)

__global__ __launch_bounds__(256) void sqdist_tile_kernel(
    const float* __restrict__ x, float* __restrict__ Z)
{
    const int b  = blockIdx.z;
    const int i0 = blockIdx.y * BM;
    const int j0 = blockIdx.x * BN;
    const float* Xb = x + (size_t)b * N_DIM * D_DIM;

    __shared__ float As[BK][BM + PADA];  // As[k][m] (k-major for float4 reads)
    __shared__ float Bs[BK][BN + PADB];

    const int tid = threadIdx.x;
    const int tx  = tid & 15;   // n-group: n0 = tx*2
    const int ty  = tid >> 4;   // m-group: m0 = ty*4

    float acc[4][2] = {{0.f,0.f},{0.f,0.f},{0.f,0.f},{0.f,0.f}};

    for (int k0 = 0; k0 < D_DIM; k0 += BK) {
        // Load A tile: 64 rows x 16 k = 1024 floats; thread t -> one float4.
        {
            const int row = tid >> 2;          // 0..63
            const int kq  = (tid & 3) * 4;     // 0,4,8,12
            float4 v = *(const float4*)(Xb + (size_t)(i0 + row) * D_DIM + k0 + kq);
            As[kq + 0][row] = v.x; As[kq + 1][row] = v.y;
            As[kq + 2][row] = v.z; As[kq + 3][row] = v.w;
        }
        // Load B tile: 32 rows x 16 k = 512 floats; threads 0..127 -> one float4.
        if (tid < 128) {
            const int row = tid >> 2;          // 0..31
            const int kq  = (tid & 3) * 4;
            float4 v = *(const float4*)(Xb + (size_t)(j0 + row) * D_DIM + k0 + kq);
            Bs[kq + 0][row] = v.x; Bs[kq + 1][row] = v.y;
            Bs[kq + 2][row] = v.z; Bs[kq + 3][row] = v.w;
        }
        __syncthreads();

        #pragma unroll
        for (int k = 0; k < BK; ++k) {
            const float4 a  = *(const float4*)&As[k][ty * 4];  // broadcast within 16 lanes
            const float2 bv = *(const float2*)&Bs[k][tx * 2];
            const float am[4] = {a.x, a.y, a.z, a.w};
            const float bn[2] = {bv.x, bv.y};
            #pragma unroll
            for (int u = 0; u < 4; ++u) {
                #pragma unroll
                for (int v2 = 0; v2 < 2; ++v2) {
                    const float dd = am[u] - bn[v2];
                    acc[u][v2] = fmaf(dd, dd, acc[u][v2]);
                }
            }
        }
        __syncthreads();
    }

    // Write Z[b][i0+ty*4+u][j0+tx*2 .. +1]
    #pragma unroll
    for (int u = 0; u < 4; ++u) {
        float2 o = make_float2(acc[u][0], acc[u][1]);
        *(float2*)(Z + ((size_t)b * N_DIM + (i0 + ty * 4 + u)) * D_DIM + j0 + tx * 2) = o;
    }
}

// ---------------- Edge pass: out[e][0..7] = sqrt(Z[b][i][j]) ---------------
// 2 threads per edge; each writes one float4 (16B/lane, fully coalesced).
__global__ __launch_bounds__(256) void edge_out_kernel(
    const int* __restrict__ eb, const int* __restrict__ ei,
    const int* __restrict__ ej, const float* __restrict__ Z,
    float* __restrict__ out, int E)
{
    const int t = blockIdx.x * 256 + threadIdx.x;
    const int e = t >> 1;
    if (e >= E) return;
    const int b = eb[e];
    const int i = ei[e];
    const int j = ej[e];
    const float z = Z[((size_t)b * N_DIM + i) * D_DIM + j];
    const float d = sqrtf(z);
    const float4 v = make_float4(d, d, d, d);
    *(float4*)(out + (size_t)e * 8 + (t & 1) * 4) = v;
}

// ---------------- Fallback (ws too small): direct per-edge wave -----------
__global__ __launch_bounds__(256) void edge_dist_direct_kernel(
    const float* __restrict__ x,
    const int* __restrict__ eb, const int* __restrict__ ei,
    const int* __restrict__ ej, float* __restrict__ out, int E)
{
    const int wave = (int)((blockIdx.x * (unsigned)blockDim.x + threadIdx.x) >> 6);
    if (wave >= E) return;
    const int lane = (int)(threadIdx.x & 63u);
    const int b = eb[wave], i = ei[wave], j = ej[wave];
    const float4 a = reinterpret_cast<const float4*>(x + ((size_t)b * N_DIM + i) * D_DIM)[lane];
    const float4 c = reinterpret_cast<const float4*>(x + ((size_t)b * N_DIM + j) * D_DIM)[lane];
    const float dx = a.x - c.x, dy = a.y - c.y, dz = a.z - c.z, dw = a.w - c.w;
    float s = dx * dx + dy * dy + dz * dz + dw * dw;
    #pragma unroll
    for (int off = 32; off >= 1; off >>= 1) s += __shfl_xor(s, off, 64);
    const float d = sqrtf(s);
    if (lane < 2)
        reinterpret_cast<float4*>(out + (size_t)wave * 8)[lane] =
            make_float4(d, d, d, d);
}

extern "C" void kernel_launch(void* const* d_in, const int* in_sizes, int n_in,
                              void* d_out, int out_size, void* d_ws, size_t ws_size,
                              hipStream_t stream) {
    const float* x  = (const float*)d_in[0];
    const int*   eb = (const int*)d_in[1];
    const int*   ei = (const int*)d_in[2];
    const int*   ej = (const int*)d_in[3];
    float* out = (float*)d_out;
    const int E = in_sizes[1];
    if (E <= 0) return;

    const size_t z_bytes = (size_t)B_DIM * N_DIM * D_DIM * sizeof(float);  // 4 MB

    if (ws_size >= z_bytes) {
        float* Z = (float*)d_ws;
        dim3 tgrid(D_DIM / BN, N_DIM / BM, B_DIM);  // (8,16,4)
        sqdist_tile_kernel<<<tgrid, 256, 0, stream>>>(x, Z);
        const int threads = 2 * E;
        edge_out_kernel<<<(threads + 255) / 256, 256, 0, stream>>>(eb, ei, ej, Z, out, E);
    } else {
        const int blocks = (E + 3) / 4;  // 4 waves/block
        edge_dist_direct_kernel<<<blocks, 256, 0, stream>>>(x, eb, ei, ej, out, E);
    }
}

// Round 3
// 25.528 us; speedup vs baseline: 3.4813x; 1.1908x over previous
//
#include <hip/hip_runtime.h>

// Problem constants from the reference (B=4, N=1024, D=256).
#define B_DIM 4
#define N_DIM 1024
#define D_DIM 256   // ej < 256 always (nonzero over last dim of x)

typedef __bf16 bf16x8 __attribute__((ext_vector_type(8)));
typedef float  f32x4  __attribute__((ext_vector_type(4)));

// ---------------- Gram kernel: Dtab[b][i][j] = ||x[b,i]-x[b,j]|| -----------
// d^2 = n_i + n_j - 2*<x_i, x_j>, Gram via mfma_f32_16x16x32_bf16.
// Block = 256 threads (4 waves as 2x2), each wave computes a 32x32 tile
// (2x2 fragments of 16x16). Tile 64(i) x 64(j). Grid (256/64, 1024/64, B).
// Fragments load straight from global (x is L2-resident, 4 MB): for this MFMA
// shape, A lane (l) needs row (l&15), k = (l>>4)*8 + 0..7 (contiguous), and
// B lane needs col (l&15) = x-row j, same contiguous k — both are 32 B row
// segments of x. Norms of the ORIGINAL f32 values accumulate alongside.
__global__ __launch_bounds__(256) void gram_dist_kernel(
    const float* __restrict__ x, float* __restrict__ Dtab)
{
    const int b  = blockIdx.z;
    const int i0 = blockIdx.y * 64;
    const int j0 = blockIdx.x * 64;
    const float* __restrict__ Xb = x + (size_t)b * N_DIM * D_DIM;

    const int lane = (int)(threadIdx.x & 63u);
    const int wid  = (int)(threadIdx.x >> 6);
    const int im0  = i0 + (wid >> 1) * 32;   // wave's i origin
    const int jm0  = j0 + (wid & 1) * 32;    // wave's j origin

    const int rsel = lane & 15;       // row/col within fragment
    const int kg   = lane >> 4;       // k-group (0..3) * 8

    f32x4 acc[2][2] = {};
    float na[2] = {0.f, 0.f};         // partial ||x_i||^2 (rows im0+fm*16+rsel)
    float nb[2] = {0.f, 0.f};         // partial ||x_j||^2 (cols jm0+fn*16+rsel)

    for (int k0 = 0; k0 < D_DIM; k0 += 32) {
        bf16x8 af[2], bf[2];
        #pragma unroll
        for (int f = 0; f < 2; ++f) {
            const float* rp = Xb + (size_t)(im0 + f * 16 + rsel) * D_DIM + k0 + kg * 8;
            float4 v0 = *(const float4*)rp;
            float4 v1 = *(const float4*)(rp + 4);
            af[f][0]=(__bf16)v0.x; af[f][1]=(__bf16)v0.y; af[f][2]=(__bf16)v0.z; af[f][3]=(__bf16)v0.w;
            af[f][4]=(__bf16)v1.x; af[f][5]=(__bf16)v1.y; af[f][6]=(__bf16)v1.z; af[f][7]=(__bf16)v1.w;
            na[f] += v0.x*v0.x + v0.y*v0.y + v0.z*v0.z + v0.w*v0.w
                   + v1.x*v1.x + v1.y*v1.y + v1.z*v1.z + v1.w*v1.w;
        }
        #pragma unroll
        for (int f = 0; f < 2; ++f) {
            const float* rp = Xb + (size_t)(jm0 + f * 16 + rsel) * D_DIM + k0 + kg * 8;
            float4 v0 = *(const float4*)rp;
            float4 v1 = *(const float4*)(rp + 4);
            bf[f][0]=(__bf16)v0.x; bf[f][1]=(__bf16)v0.y; bf[f][2]=(__bf16)v0.z; bf[f][3]=(__bf16)v0.w;
            bf[f][4]=(__bf16)v1.x; bf[f][5]=(__bf16)v1.y; bf[f][6]=(__bf16)v1.z; bf[f][7]=(__bf16)v1.w;
            nb[f] += v0.x*v0.x + v0.y*v0.y + v0.z*v0.z + v0.w*v0.w
                   + v1.x*v1.x + v1.y*v1.y + v1.z*v1.z + v1.w*v1.w;
        }
        #pragma unroll
        for (int fm = 0; fm < 2; ++fm)
            #pragma unroll
            for (int fn = 0; fn < 2; ++fn)
                acc[fm][fn] = __builtin_amdgcn_mfma_f32_16x16x32_bf16(
                    af[fm], bf[fn], acc[fm][fn], 0, 0, 0);
    }

    // Full norms: reduce over the 4 k-groups (lanes sharing (lane&15)).
    #pragma unroll
    for (int f = 0; f < 2; ++f) {
        na[f] += __shfl_xor(na[f], 16, 64);
        na[f] += __shfl_xor(na[f], 32, 64);
        nb[f] += __shfl_xor(nb[f], 16, 64);
        nb[f] += __shfl_xor(nb[f], 32, 64);
    }

    // C/D layout (m89-verified): col = lane&15, row = (lane>>4)*4 + reg.
    #pragma unroll
    for (int fm = 0; fm < 2; ++fm) {
        #pragma unroll
        for (int fn = 0; fn < 2; ++fn) {
            const int col = jm0 + fn * 16 + rsel;
            const float nj = nb[fn];
            #pragma unroll
            for (int r = 0; r < 4; ++r) {
                const int r16 = kg * 4 + r;
                const int row = im0 + fm * 16 + r16;
                const float ni = __shfl(na[fm], r16, 64);
                float d2 = ni + nj - 2.0f * acc[fm][fn][r];
                float d  = sqrtf(fmaxf(d2, 0.0f));
                if (row == col) d = 0.0f;   // exact zero for i==j edges
                Dtab[((size_t)b * N_DIM + row) * D_DIM + col] = d;
            }
        }
    }
}

// ---------------- Edge pass: out[e][0..7] = Dtab[b][i][j] ------------------
// 2 threads per edge; each writes one float4 (16 B, coalesced). No sqrt here.
__global__ __launch_bounds__(256) void edge_out_kernel(
    const int* __restrict__ eb, const int* __restrict__ ei,
    const int* __restrict__ ej, const float* __restrict__ Dtab,
    float* __restrict__ out, int E)
{
    const int t = blockIdx.x * 256 + (int)threadIdx.x;
    const int e = t >> 1;
    if (e >= E) return;
    const float d = Dtab[((size_t)eb[e] * N_DIM + ei[e]) * D_DIM + ej[e]];
    *(float4*)(out + (size_t)e * 8 + (t & 1) * 4) = make_float4(d, d, d, d);
}

// ---------------- Fallback (ws too small): direct per-edge wave ------------
__global__ __launch_bounds__(256) void edge_dist_direct_kernel(
    const float* __restrict__ x,
    const int* __restrict__ eb, const int* __restrict__ ei,
    const int* __restrict__ ej, float* __restrict__ out, int E)
{
    const int wave = (int)((blockIdx.x * (unsigned)blockDim.x + threadIdx.x) >> 6);
    if (wave >= E) return;
    const int lane = (int)(threadIdx.x & 63u);
    const int b = eb[wave], i = ei[wave], j = ej[wave];
    const float4 a = reinterpret_cast<const float4*>(x + ((size_t)b * N_DIM + i) * D_DIM)[lane];
    const float4 c = reinterpret_cast<const float4*>(x + ((size_t)b * N_DIM + j) * D_DIM)[lane];
    const float dx = a.x - c.x, dy = a.y - c.y, dz = a.z - c.z, dw = a.w - c.w;
    float s = dx * dx + dy * dy + dz * dz + dw * dw;
    #pragma unroll
    for (int off = 32; off >= 1; off >>= 1) s += __shfl_xor(s, off, 64);
    const float d = sqrtf(s);
    if (lane < 2)
        reinterpret_cast<float4*>(out + (size_t)wave * 8)[lane] =
            make_float4(d, d, d, d);
}

extern "C" void kernel_launch(void* const* d_in, const int* in_sizes, int n_in,
                              void* d_out, int out_size, void* d_ws, size_t ws_size,
                              hipStream_t stream) {
    const float* x  = (const float*)d_in[0];
    const int*   eb = (const int*)d_in[1];
    const int*   ei = (const int*)d_in[2];
    const int*   ej = (const int*)d_in[3];
    float* out = (float*)d_out;
    const int E = in_sizes[1];
    if (E <= 0) return;

    const size_t dtab_bytes = (size_t)B_DIM * N_DIM * D_DIM * sizeof(float);  // 4 MB

    if (ws_size >= dtab_bytes) {
        float* Dtab = (float*)d_ws;
        dim3 ggrid(D_DIM / 64, N_DIM / 64, B_DIM);   // (4, 16, 4) = 256 blocks
        gram_dist_kernel<<<ggrid, 256, 0, stream>>>(x, Dtab);
        const int threads = 2 * E;
        edge_out_kernel<<<(threads + 255) / 256, 256, 0, stream>>>(eb, ei, ej, Dtab, out, E);
    } else {
        const int blocks = (E + 3) / 4;  // 4 waves/block
        edge_dist_direct_kernel<<<blocks, 256, 0, stream>>>(x, eb, ei, ej, out, E);
    }
}